// Round 1
// baseline (267.510 us; speedup 1.0000x reference)
//
#include <hip/hip_runtime.h>

// 3D spatial transformer (trilinear warp), voxelmorph semantics.
// vol: [B=2, X=160, Y=192, Z=160, C=1] fp32
// trf: [B=2, X=160, Y=192, Z=160, 3]  fp32 (dense displacement, 'ij' indexing)
// out: same shape as vol, fp32.

#define NXD 160
#define NYD 192
#define NZD 160
#define NVOX (NXD * NYD * NZD)        // 4,915,200
#define NBATCH 2
#define NTOT (NBATCH * NVOX)          // 9,830,400

__global__ __launch_bounds__(256)
void warp3d_kernel(const float* __restrict__ vol,
                   const float* __restrict__ trf,
                   float* __restrict__ out) {
    int i = blockIdx.x * blockDim.x + threadIdx.x;
    if (i >= NTOT) return;

    // decompose linear index -> (b, x, y, z); z contiguous
    int z  = i % NZD;
    int t  = i / NZD;
    int y  = t % NYD;
    int t2 = t / NYD;
    int x  = t2 % NXD;
    int b  = t2 / NXD;

    // displacement (stride-3 packed)
    size_t ti = 3ull * (size_t)i;
    float tx = trf[ti + 0];
    float ty = trf[ti + 1];
    float tz = trf[ti + 2];

    // sample location = identity + displacement, clamped to border
    float lx = fminf(fmaxf((float)x + tx, 0.0f), (float)(NXD - 1));
    float ly = fminf(fmaxf((float)y + ty, 0.0f), (float)(NYD - 1));
    float lz = fminf(fmaxf((float)z + tz, 0.0f), (float)(NZD - 1));

    float fx = floorf(lx), fy = floorf(ly), fz = floorf(lz);
    int x0 = (int)fx, y0 = (int)fy, z0 = (int)fz;     // in [0, s-1] after clamp
    int x1 = min(x0 + 1, NXD - 1);
    int y1 = min(y0 + 1, NYD - 1);
    int z1 = min(z0 + 1, NZD - 1);

    // lower-corner weights d1 = loc1 - loc; upper = 1 - d1 (matches reference,
    // including the clamped-border case where loc1==loc0 -> d1=0).
    float wx0 = (float)x1 - lx;
    float wy0 = (float)y1 - ly;
    float wz0 = (float)z1 - lz;
    float wx1 = 1.0f - wx0;
    float wy1 = 1.0f - wy0;
    float wz1 = 1.0f - wz0;

    const float* vb = vol + (size_t)b * NVOX;
    size_t ox0 = (size_t)x0 * (NYD * NZD);
    size_t ox1 = (size_t)x1 * (NYD * NZD);
    int    oy0 = y0 * NZD;
    int    oy1 = y1 * NZD;

    float v000 = vb[ox0 + oy0 + z0];
    float v001 = vb[ox0 + oy0 + z1];
    float v010 = vb[ox0 + oy1 + z0];
    float v011 = vb[ox0 + oy1 + z1];
    float v100 = vb[ox1 + oy0 + z0];
    float v101 = vb[ox1 + oy0 + z1];
    float v110 = vb[ox1 + oy1 + z0];
    float v111 = vb[ox1 + oy1 + z1];

    float r = wx0 * (wy0 * (wz0 * v000 + wz1 * v001) +
                     wy1 * (wz0 * v010 + wz1 * v011)) +
              wx1 * (wy0 * (wz0 * v100 + wz1 * v101) +
                     wy1 * (wz0 * v110 + wz1 * v111));

    out[i] = r;
}

extern "C" void kernel_launch(void* const* d_in, const int* in_sizes, int n_in,
                              void* d_out, int out_size, void* d_ws, size_t ws_size,
                              hipStream_t stream) {
    const float* vol = (const float*)d_in[0];
    const float* trf = (const float*)d_in[1];
    float* out = (float*)d_out;

    int threads = 256;
    int blocks = (NTOT + threads - 1) / threads;   // 38400 blocks
    warp3d_kernel<<<blocks, threads, 0, stream>>>(vol, trf, out);
}

// Round 2
// 253.949 us; speedup vs baseline: 1.0534x; 1.0534x over previous
//
#include <hip/hip_runtime.h>

// 3D spatial transformer (trilinear warp), voxelmorph semantics.
// vol: [B=2, X=160, Y=192, Z=160, C=1] fp32
// trf: [B=2, X=160, Y=192, Z=160, 3]  fp32 (dense displacement, 'ij' indexing)
// out: same shape as vol, fp32.
//
// R2: latency/vmem-issue bound fix — 4 z-consecutive voxels per thread,
// z-pair dwordx2 gathers (8 -> 4 gathers/voxel), float4 trf loads + store.

#define NXD 160
#define NYD 192
#define NZD 160
#define NVOX (NXD * NYD * NZD)        // 4,915,200
#define NBATCH 2
#define NTOT (NBATCH * NVOX)          // 9,830,400
#define VPT 4                         // voxels per thread (z-consecutive)
#define NTHREADS (NTOT / VPT)         // 2,457,600

typedef float f2a4 __attribute__((ext_vector_type(2), aligned(4)));
typedef float f4   __attribute__((ext_vector_type(4)));

__global__ __launch_bounds__(256)
void warp3d_kernel(const float* __restrict__ vol,
                   const float* __restrict__ trf,
                   float* __restrict__ out) {
    int tid = blockIdx.x * 256 + threadIdx.x;
    if (tid >= NTHREADS) return;       // exact multiple; kept for safety

    // thread handles voxels [4*tid, 4*tid+4), z-consecutive (NZD % 4 == 0)
    int zq = tid % (NZD / VPT);        // which z-quad
    int r  = tid / (NZD / VPT);
    int y  = r % NYD;
    int r2 = r / NYD;
    int x  = r2 % NXD;
    int b  = r2 / NXD;
    int zbase = zq * VPT;

    // trf for 4 voxels = 12 floats = 3 aligned float4 loads
    const f4* trfv = (const f4*)(trf + (size_t)tid * 12);
    f4 t0 = trfv[0];
    f4 t1 = trfv[1];
    f4 t2 = trfv[2];
    float tx[VPT] = {t0.x, t0.w, t1.z, t2.y};
    float ty[VPT] = {t0.y, t1.x, t1.w, t2.z};
    float tz[VPT] = {t0.z, t1.y, t2.x, t2.w};

    const float* vb = vol + (size_t)b * NVOX;

    // ---- phase 1: addresses + weights + issue all 16 gathers ----
    f2a4  g00[VPT], g01[VPT], g10[VPT], g11[VPT];
    float wx0[VPT], wy0[VPT], wz0[VPT];
    int   selz[VPT];                   // 1 if z0 == zb (normal), 0 if clamped top

#pragma unroll
    for (int j = 0; j < VPT; ++j) {
        float lx = fminf(fmaxf((float)x + tx[j], 0.0f), (float)(NXD - 1));
        float ly = fminf(fmaxf((float)y + ty[j], 0.0f), (float)(NYD - 1));
        float lz = fminf(fmaxf((float)(zbase + j) + tz[j], 0.0f), (float)(NZD - 1));

        int x0 = (int)lx;              // lx >= 0, floor == trunc
        int y0 = (int)ly;
        int z0 = (int)lz;
        int x1 = min(x0 + 1, NXD - 1);
        int y1 = min(y0 + 1, NYD - 1);
        int z1 = min(z0 + 1, NZD - 1);

        // lower-corner weights d1 = loc1 - loc (0 at clamped border)
        wx0[j] = (float)x1 - lx;
        wy0[j] = (float)y1 - ly;
        wz0[j] = (float)z1 - lz;

        int zb = min(z0, NZD - 2);     // base of the z-pair load
        selz[j] = (z0 == zb);

        size_t ox0 = (size_t)x0 * (NYD * NZD);
        size_t ox1 = (size_t)x1 * (NYD * NZD);
        int    oy0 = y0 * NZD;
        int    oy1 = y1 * NZD;

        g00[j] = *(const f2a4*)(vb + ox0 + oy0 + zb);
        g01[j] = *(const f2a4*)(vb + ox0 + oy1 + zb);
        g10[j] = *(const f2a4*)(vb + ox1 + oy0 + zb);
        g11[j] = *(const f2a4*)(vb + ox1 + oy1 + zb);
    }

    // ---- phase 2: blend ----
    f4 res;
#pragma unroll
    for (int j = 0; j < VPT; ++j) {
        // z-pair select: v_z1 is always .y; v_z0 is .x unless clamped (z0==z1)
        float v000 = selz[j] ? g00[j].x : g00[j].y;
        float v010 = selz[j] ? g01[j].x : g01[j].y;
        float v100 = selz[j] ? g10[j].x : g10[j].y;
        float v110 = selz[j] ? g11[j].x : g11[j].y;
        float v001 = g00[j].y;
        float v011 = g01[j].y;
        float v101 = g10[j].y;
        float v111 = g11[j].y;

        float wx1 = 1.0f - wx0[j];
        float wy1 = 1.0f - wy0[j];
        float wz1 = 1.0f - wz0[j];

        float rj = wx0[j] * (wy0[j] * (wz0[j] * v000 + wz1 * v001) +
                             wy1    * (wz0[j] * v010 + wz1 * v011)) +
                   wx1    * (wy0[j] * (wz0[j] * v100 + wz1 * v101) +
                             wy1    * (wz0[j] * v110 + wz1 * v111));
        if (j == 0) res.x = rj;
        else if (j == 1) res.y = rj;
        else if (j == 2) res.z = rj;
        else res.w = rj;
    }

    *(f4*)(out + (size_t)tid * VPT) = res;
}

extern "C" void kernel_launch(void* const* d_in, const int* in_sizes, int n_in,
                              void* d_out, int out_size, void* d_ws, size_t ws_size,
                              hipStream_t stream) {
    const float* vol = (const float*)d_in[0];
    const float* trf = (const float*)d_in[1];
    float* out = (float*)d_out;

    int threads = 256;
    int blocks = (NTHREADS + threads - 1) / threads;   // 9600 blocks
    warp3d_kernel<<<blocks, threads, 0, stream>>>(vol, trf, out);
}

// Round 3
// 225.695 us; speedup vs baseline: 1.1853x; 1.1252x over previous
//
#include <hip/hip_runtime.h>

// 3D spatial transformer (trilinear warp), voxelmorph semantics.
// vol: [B=2, X=160, Y=192, Z=160, C=1] fp32
// trf: [B=2, X=160, Y=192, Z=160, 3]  fp32 (dense displacement)
// out: same shape as vol, fp32.
//
// R3: the global-gather path is TA/address-throughput bound (~1 line-req/cyc/CU).
// Stage vol tiles in LDS (16x16x32 floats, halo 4/4/8) and gather via ds_read2;
// rare out-of-tile samples (unbounded N(0,1) displacement) fall back to global.

#define NXD 160
#define NYD 192
#define NZD 160
#define NVOX (NXD * NYD * NZD)
#define NBATCH 2

#define TX 8
#define TY 8
#define TZ 16
#define LXT 16            // staged x extent  (lox = x0t - 4)
#define LYT 16            // staged y extent  (loy = y0t - 4)
#define LZT 32            // staged z extent  (loz = z0t - 8)
#define LDS_N (LXT * LYT * LZT)   // 8192 floats = 32 KB

#define TILES_X (NXD / TX)   // 20
#define TILES_Y (NYD / TY)   // 24
#define TILES_Z (NZD / TZ)   // 10
#define NBLOCKS (NBATCH * TILES_X * TILES_Y * TILES_Z)   // 9600

typedef float f4 __attribute__((ext_vector_type(4)));

__global__ __launch_bounds__(256)
void warp3d_kernel(const float* __restrict__ vol,
                   const float* __restrict__ trf,
                   float* __restrict__ out) {
    __shared__ float tile[LDS_N];

    int bid = blockIdx.x;
    int tz = bid % TILES_Z;
    int r  = bid / TILES_Z;
    int ty = r % TILES_Y;
    int r2 = r / TILES_Y;
    int tx = r2 % TILES_X;
    int b  = r2 / TILES_X;

    int x0t = tx * TX, y0t = ty * TY, z0t = tz * TZ;
    int lox = x0t - 4, loy = y0t - 4, loz = z0t - 8;

    const float* vb = vol + (size_t)b * NVOX;

    int t = threadIdx.x;
    // compute-phase voxel quad for this thread (4 z-consecutive voxels)
    int zq = t & 3, yq = (t >> 2) & 7, xq = t >> 5;
    int x = x0t + xq, y = y0t + yq, zb0 = z0t + zq * 4;
    size_t vox_i = (((size_t)b * NXD + x) * NYD + y) * NZD + zb0;

    // prefetch trf (12 floats = 3 aligned float4) — overlaps staging latency
    const f4* trfv = (const f4*)(trf + vox_i * 3);
    f4 t0 = trfv[0], t1 = trfv[1], t2 = trfv[2];

    // ---- stage vol tile into LDS ----
    bool interior = (lox >= 0) & (lox + LXT <= NXD) &
                    (loy >= 0) & (loy + LYT <= NYD) &
                    (loz >= 0) & (loz + LZT <= NZD);
    if (interior) {
        const float* gbase = vb + ((size_t)(lox * NYD + loy) * NZD + loz);
        int w = t >> 6;          // wave id 0..3
        int l = t & 63;          // lane
#pragma unroll
        for (int it = 0; it < 8; ++it) {
            int chunk = it * 4 + w;            // 0..31, wave-uniform
            int p = chunk * 256 + l * 4;       // this lane's first float slot
            int zi = p & 31, yi = (p >> 5) & 15, xi = p >> 9;
            const float* g = gbase + (size_t)xi * (NYD * NZD) + yi * NZD + zi;
            __builtin_amdgcn_global_load_lds(
                (const __attribute__((address_space(1))) void*)g,
                (__attribute__((address_space(3))) void*)&tile[chunk * 256],
                16, 0, 0);
        }
    } else {
#pragma unroll 4
        for (int it = 0; it < LDS_N / 256; ++it) {   // 32 iters
            int e = it * 256 + t;
            int zi = e & 31, yi = (e >> 5) & 15, xi = e >> 9;
            int gx = min(max(lox + xi, 0), NXD - 1);
            int gy = min(max(loy + yi, 0), NYD - 1);
            int gz = min(max(loz + zi, 0), NZD - 1);
            tile[e] = vb[(size_t)(gx * NYD + gy) * NZD + gz];
        }
    }
    __syncthreads();

    // ---- gather + trilinear blend, 4 voxels ----
    float dxa[4] = {t0.x, t0.w, t1.z, t2.y};
    float dya[4] = {t0.y, t1.x, t1.w, t2.z};
    float dza[4] = {t0.z, t1.y, t2.x, t2.w};

    float res[4];
#pragma unroll
    for (int j = 0; j < 4; ++j) {
        float lx = fminf(fmaxf((float)x + dxa[j], 0.0f), (float)(NXD - 1));
        float ly = fminf(fmaxf((float)y + dya[j], 0.0f), (float)(NYD - 1));
        float lz = fminf(fmaxf((float)(zb0 + j) + dza[j], 0.0f), (float)(NZD - 1));
        float fx = floorf(lx), fy = floorf(ly), fz = floorf(lz);
        int x0 = (int)fx, y0 = (int)fy, z0 = (int)fz;
        // lower-corner weights d1 = loc1 - loc (0 at clamped top border)
        float wx0 = fminf(fx + 1.0f, (float)(NXD - 1)) - lx;
        float wy0 = fminf(fy + 1.0f, (float)(NYD - 1)) - ly;
        float wz0 = fminf(fz + 1.0f, (float)(NZD - 1)) - lz;

        int ix = x0 - lox, iy = y0 - loy, iz = z0 - loz;
        bool ok = ((unsigned)ix <= LXT - 2) & ((unsigned)iy <= LYT - 2) &
                  ((unsigned)iz <= LZT - 2);
        int a = ok ? ((ix * LYT + iy) * LZT + iz) : 0;   // safe addr when !ok

        float v000 = tile[a],                 v001 = tile[a + 1];
        float v010 = tile[a + LZT],           v011 = tile[a + LZT + 1];
        float v100 = tile[a + LYT * LZT],     v101 = tile[a + LYT * LZT + 1];
        float v110 = tile[a + LYT * LZT + LZT], v111 = tile[a + LYT * LZT + LZT + 1];

        if (!ok) {   // rare: sample outside staged tile -> global gather
            int x1 = min(x0 + 1, NXD - 1);
            int y1 = min(y0 + 1, NYD - 1);
            int z1 = min(z0 + 1, NZD - 1);
            size_t o00 = (size_t)(x0 * NYD + y0) * NZD;
            size_t o01 = (size_t)(x0 * NYD + y1) * NZD;
            size_t o10 = (size_t)(x1 * NYD + y0) * NZD;
            size_t o11 = (size_t)(x1 * NYD + y1) * NZD;
            v000 = vb[o00 + z0]; v001 = vb[o00 + z1];
            v010 = vb[o01 + z0]; v011 = vb[o01 + z1];
            v100 = vb[o10 + z0]; v101 = vb[o10 + z1];
            v110 = vb[o11 + z0]; v111 = vb[o11 + z1];
        }

        float wx1 = 1.0f - wx0, wy1 = 1.0f - wy0, wz1 = 1.0f - wz0;
        res[j] = wx0 * (wy0 * (wz0 * v000 + wz1 * v001) +
                        wy1 * (wz0 * v010 + wz1 * v011)) +
                 wx1 * (wy0 * (wz0 * v100 + wz1 * v101) +
                        wy1 * (wz0 * v110 + wz1 * v111));
    }

    f4 o;
    o.x = res[0]; o.y = res[1]; o.z = res[2]; o.w = res[3];
    *(f4*)(out + vox_i) = o;
}

extern "C" void kernel_launch(void* const* d_in, const int* in_sizes, int n_in,
                              void* d_out, int out_size, void* d_ws, size_t ws_size,
                              hipStream_t stream) {
    const float* vol = (const float*)d_in[0];
    const float* trf = (const float*)d_in[1];
    float* out = (float*)d_out;

    warp3d_kernel<<<NBLOCKS, 256, 0, stream>>>(vol, trf, out);
}

// Round 4
// 222.566 us; speedup vs baseline: 1.2019x; 1.0141x over previous
//
#include <hip/hip_runtime.h>

// 3D spatial transformer (trilinear warp), voxelmorph semantics.
// vol: [B=2, X=160, Y=192, Z=160, C=1] fp32
// trf: [B=2, X=160, Y=192, Z=160, 3]  fp32 (dense displacement)
// out: same shape as vol, fp32.
//
// R4: occupancy + halo amortization. 512-thread blocks, tile 8x16x16 voxels,
// staged 16x24x32 floats (48 KB LDS -> 3 blocks/CU = 24 waves = 75% occ,
// staged/computed ratio 8x -> 6x). Gathers served from LDS; rare out-of-tile
// samples (N(0,1) displacement tails) fall back to global gather.

#define NXD 160
#define NYD 192
#define NZD 160
#define NVOX (NXD * NYD * NZD)
#define NBATCH 2

#define TXT 8
#define TYT 16
#define TZT 16
#define LXT 16            // staged x extent (lox = x0t - 4)
#define LYT 24            // staged y extent (loy = y0t - 4)
#define LZT 32            // staged z extent (loz = z0t - 8)
#define LDS_N (LXT * LYT * LZT)   // 12288 floats = 48 KB

#define TILES_X (NXD / TXT)   // 20
#define TILES_Y (NYD / TYT)   // 12
#define TILES_Z (NZD / TZT)   // 10
#define NBLOCKS (NBATCH * TILES_X * TILES_Y * TILES_Z)   // 4800

typedef float f4 __attribute__((ext_vector_type(4)));

__global__ __launch_bounds__(512)
void warp3d_kernel(const float* __restrict__ vol,
                   const float* __restrict__ trf,
                   float* __restrict__ out) {
    __shared__ float tile[LDS_N];

    int bid = blockIdx.x;
    int tz = bid % TILES_Z;
    int r  = bid / TILES_Z;
    int ty = r % TILES_Y;
    int r2 = r / TILES_Y;
    int tx = r2 % TILES_X;
    int b  = r2 / TILES_X;

    int x0t = tx * TXT, y0t = ty * TYT, z0t = tz * TZT;
    int lox = x0t - 4, loy = y0t - 4, loz = z0t - 8;

    const float* vb = vol + (size_t)b * NVOX;

    int t = threadIdx.x;
    // compute-phase voxel quad: 4 z-consecutive voxels per thread
    int zq = t & 3;             // 4 z-quads (TZT/4)
    int yq = (t >> 2) & 15;     // 16 y
    int xq = t >> 6;            // 8 x
    int x = x0t + xq, y = y0t + yq, zb0 = z0t + zq * 4;
    size_t vox_i = (((size_t)b * NXD + x) * NYD + y) * NZD + zb0;

    // prefetch trf (12 floats = 3 aligned float4) — overlaps staging latency
    const f4* trfv = (const f4*)(trf + vox_i * 3);
    f4 t0 = trfv[0], t1 = trfv[1], t2 = trfv[2];

    // ---- stage vol tile into LDS ----
    bool interior = (lox >= 0) & (lox + LXT <= NXD) &
                    (loy >= 0) & (loy + LYT <= NYD) &
                    (loz >= 0) & (loz + LZT <= NZD);
    if (interior) {
        const float* gbase = vb + ((size_t)(lox * NYD + loy) * NZD + loz);
        int w = t >> 6;          // wave id 0..7
        int l = t & 63;          // lane
#pragma unroll
        for (int it = 0; it < 6; ++it) {
            int chunk = it * 8 + w;            // 0..47, wave-uniform
            int p = chunk * 256 + l * 4;       // lane's first float slot
            int zi = p & 31;
            int rest = p >> 5;
            int yi = rest % LYT;
            int xi = rest / LYT;
            const float* g = gbase + (size_t)xi * (NYD * NZD) + yi * NZD + zi;
            __builtin_amdgcn_global_load_lds(
                (const __attribute__((address_space(1))) void*)g,
                (__attribute__((address_space(3))) void*)&tile[chunk * 256],
                16, 0, 0);
        }
    } else {
#pragma unroll 4
        for (int it = 0; it < LDS_N / 512; ++it) {   // 24 iters
            int e = it * 512 + t;
            int zi = e & 31;
            int rest = e >> 5;
            int yi = rest % LYT;
            int xi = rest / LYT;
            int gx = min(max(lox + xi, 0), NXD - 1);
            int gy = min(max(loy + yi, 0), NYD - 1);
            int gz = min(max(loz + zi, 0), NZD - 1);
            tile[e] = vb[(size_t)(gx * NYD + gy) * NZD + gz];
        }
    }
    __syncthreads();

    // ---- gather + trilinear blend, 4 voxels ----
    float dxa[4] = {t0.x, t0.w, t1.z, t2.y};
    float dya[4] = {t0.y, t1.x, t1.w, t2.z};
    float dza[4] = {t0.z, t1.y, t2.x, t2.w};

    float res[4];
#pragma unroll
    for (int j = 0; j < 4; ++j) {
        float lx = fminf(fmaxf((float)x + dxa[j], 0.0f), (float)(NXD - 1));
        float ly = fminf(fmaxf((float)y + dya[j], 0.0f), (float)(NYD - 1));
        float lz = fminf(fmaxf((float)(zb0 + j) + dza[j], 0.0f), (float)(NZD - 1));
        float fx = floorf(lx), fy = floorf(ly), fz = floorf(lz);
        int x0 = (int)fx, y0 = (int)fy, z0 = (int)fz;
        // lower-corner weights d1 = loc1 - loc (0 at clamped top border)
        float wx0 = fminf(fx + 1.0f, (float)(NXD - 1)) - lx;
        float wy0 = fminf(fy + 1.0f, (float)(NYD - 1)) - ly;
        float wz0 = fminf(fz + 1.0f, (float)(NZD - 1)) - lz;

        int ix = x0 - lox, iy = y0 - loy, iz = z0 - loz;
        bool ok = ((unsigned)ix <= LXT - 2) & ((unsigned)iy <= LYT - 2) &
                  ((unsigned)iz <= LZT - 2);
        int a = ok ? ((ix * LYT + iy) * LZT + iz) : 0;   // safe addr when !ok

        float v000 = tile[a],                   v001 = tile[a + 1];
        float v010 = tile[a + LZT],             v011 = tile[a + LZT + 1];
        float v100 = tile[a + LYT * LZT],       v101 = tile[a + LYT * LZT + 1];
        float v110 = tile[a + LYT * LZT + LZT], v111 = tile[a + LYT * LZT + LZT + 1];

        if (!ok) {   // rare: sample outside staged tile -> global gather
            int x1 = min(x0 + 1, NXD - 1);
            int y1 = min(y0 + 1, NYD - 1);
            int z1 = min(z0 + 1, NZD - 1);
            size_t o00 = (size_t)(x0 * NYD + y0) * NZD;
            size_t o01 = (size_t)(x0 * NYD + y1) * NZD;
            size_t o10 = (size_t)(x1 * NYD + y0) * NZD;
            size_t o11 = (size_t)(x1 * NYD + y1) * NZD;
            v000 = vb[o00 + z0]; v001 = vb[o00 + z1];
            v010 = vb[o01 + z0]; v011 = vb[o01 + z1];
            v100 = vb[o10 + z0]; v101 = vb[o10 + z1];
            v110 = vb[o11 + z0]; v111 = vb[o11 + z1];
        }

        float wx1 = 1.0f - wx0, wy1 = 1.0f - wy0, wz1 = 1.0f - wz0;
        res[j] = wx0 * (wy0 * (wz0 * v000 + wz1 * v001) +
                        wy1 * (wz0 * v010 + wz1 * v011)) +
                 wx1 * (wy0 * (wz0 * v100 + wz1 * v101) +
                        wy1 * (wz0 * v110 + wz1 * v111));
    }

    f4 o;
    o.x = res[0]; o.y = res[1]; o.z = res[2]; o.w = res[3];
    *(f4*)(out + vox_i) = o;
}

extern "C" void kernel_launch(void* const* d_in, const int* in_sizes, int n_in,
                              void* d_out, int out_size, void* d_ws, size_t ws_size,
                              hipStream_t stream) {
    const float* vol = (const float*)d_in[0];
    const float* trf = (const float*)d_in[1];
    float* out = (float*)d_out;

    warp3d_kernel<<<NBLOCKS, 512, 0, stream>>>(vol, trf, out);
}